// Round 1
// baseline (131.865 us; speedup 1.0000x reference)
//
#include <hip/hip_runtime.h>
#include <hip/hip_bf16.h>

#define M_TOTAL 65536
#define HIDDEN  1024
#define N_TOTAL 152
#define OFF_CLS (M_TOTAL * 8)                  // 524288
#define OFF_REG (OFF_CLS + M_TOTAL * 128)      // 8912896

typedef __attribute__((ext_vector_type(8))) short  bf16x8;
typedef __attribute__((ext_vector_type(4))) float  f32x4;
typedef __attribute__((ext_vector_type(4))) unsigned short u16x4;

__device__ __forceinline__ unsigned short f2bf(float f) {
    union { float f; unsigned int u; } v; v.f = f;
    unsigned int r = v.u + 0x7FFFu + ((v.u >> 16) & 1u);   // RNE
    return (unsigned short)(r >> 16);
}

// ---- pre-kernel: fuse conf_w/cls_w/reg_w -> bf16 W[160][1024] in ws (rows 152..159 zero) ----
__global__ void convert_w_kernel(const float* __restrict__ conf_w,
                                 const float* __restrict__ cls_w,
                                 const float* __restrict__ reg_w,
                                 unsigned short* __restrict__ wbf) {
    const int r = blockIdx.x;        // 0..159
    const int c = threadIdx.x * 4;   // 256 threads * 4 = 1024
    const float* src;
    if      (r <   8) src = conf_w + (size_t)r * HIDDEN;
    else if (r < 136) src = cls_w  + (size_t)(r -   8) * HIDDEN;
    else if (r < 152) src = reg_w  + (size_t)(r - 136) * HIDDEN;
    else              src = nullptr;
    unsigned short* dst = wbf + (size_t)r * HIDDEN;
    u16x4 o;
    if (src) {
        f32x4 v = *(const f32x4*)(src + c);
        o[0] = f2bf(v[0]); o[1] = f2bf(v[1]); o[2] = f2bf(v[2]); o[3] = f2bf(v[3]);
    } else {
        o[0] = 0; o[1] = 0; o[2] = 0; o[3] = 0;
    }
    *(u16x4*)(dst + c) = o;
}

// ---- main kernel: per-wave 32 rows x all 152 cols, no LDS, no barriers ----
__global__ __launch_bounds__(256) void ssd_mfma_kernel(
    const float* __restrict__ hs,
    const unsigned short* __restrict__ wbf,
    const float* __restrict__ conf_b,
    const float* __restrict__ cls_b,
    const float* __restrict__ reg_b,
    float* __restrict__ out) {

    const int tid  = threadIdx.x;
    const int wave = tid >> 6;
    const int lane = tid & 63;
    const int c    = lane & 15;   // A row-in-tile / B col-in-tile / D col
    const int kg   = lane >> 4;   // k-group 0..3

    const int Rbase = blockIdx.x * 128 + wave * 32;

    const float* a0p = hs + (size_t)(Rbase +      c) * HIDDEN + kg * 8;
    const float* a1p = hs + (size_t)(Rbase + 16 + c) * HIDDEN + kg * 8;
    const unsigned short* bp = wbf + (size_t)c * HIDDEN + kg * 8;

    f32x4 acc[2][10];
    #pragma unroll
    for (int t = 0; t < 2; ++t)
        #pragma unroll
        for (int nt = 0; nt < 10; ++nt) {
            f32x4 z = {0.f, 0.f, 0.f, 0.f};
            acc[t][nt] = z;
        }

    // prefetch A chunk for kk = 0
    f32x4 a0lo = *(const f32x4*)(a0p);
    f32x4 a0hi = *(const f32x4*)(a0p + 4);
    f32x4 a1lo = *(const f32x4*)(a1p);
    f32x4 a1hi = *(const f32x4*)(a1p + 4);

    for (int kk = 0; kk < HIDDEN; kk += 32) {
        // B fragments for this K-step (L2-resident bf16 weights)
        bf16x8 bfrag[10];
        #pragma unroll
        for (int nt = 0; nt < 10; ++nt)
            bfrag[nt] = *(const bf16x8*)(bp + kk + nt * 16 * HIDDEN);

        // convert current A chunk to bf16 fragments
        bf16x8 af0, af1;
        #pragma unroll
        for (int j = 0; j < 4; ++j) {
            af0[j]     = (short)f2bf(a0lo[j]);
            af0[4 + j] = (short)f2bf(a0hi[j]);
            af1[j]     = (short)f2bf(a1lo[j]);
            af1[4 + j] = (short)f2bf(a1hi[j]);
        }

        // issue next A chunk loads (stay in flight across the MFMAs)
        const int kn = (kk + 32 < HIDDEN) ? (kk + 32) : kk;
        a0lo = *(const f32x4*)(a0p + kn);
        a0hi = *(const f32x4*)(a0p + kn + 4);
        a1lo = *(const f32x4*)(a1p + kn);
        a1hi = *(const f32x4*)(a1p + kn + 4);

        #pragma unroll
        for (int nt = 0; nt < 10; ++nt) {
            acc[0][nt] = __builtin_amdgcn_mfma_f32_16x16x32_bf16(af0, bfrag[nt], acc[0][nt], 0, 0, 0);
            acc[1][nt] = __builtin_amdgcn_mfma_f32_16x16x32_bf16(af1, bfrag[nt], acc[1][nt], 0, 0, 0);
        }
    }

    // epilogue: bias + scatter into conf/cls/reg regions
    #pragma unroll
    for (int nt = 0; nt < 10; ++nt) {
        const int n = nt * 16 + c;
        if (n >= N_TOTAL) continue;           // pad cols 152..159
        float bias; size_t obase; int ostride;
        if      (n <   8) { bias = conf_b[n];       obase = (size_t)n;                   ostride = 8;   }
        else if (n < 136) { bias = cls_b[n - 8];    obase = OFF_CLS + (size_t)(n - 8);   ostride = 128; }
        else              { bias = reg_b[n - 136];  obase = OFF_REG + (size_t)(n - 136); ostride = 16;  }
        #pragma unroll
        for (int t = 0; t < 2; ++t) {
            const int mb = Rbase + t * 16 + kg * 4;   // D row = (lane>>4)*4 + reg
            #pragma unroll
            for (int i = 0; i < 4; ++i)
                out[obase + (size_t)(mb + i) * ostride] = acc[t][nt][i] + bias;
        }
    }
}

// ---- exact fp32 fallback (only if ws too small; correctness insurance) ----
__global__ void ssd_naive_kernel(const float* __restrict__ hs,
                                 const float* __restrict__ conf_w, const float* __restrict__ conf_b,
                                 const float* __restrict__ cls_w,  const float* __restrict__ cls_b,
                                 const float* __restrict__ reg_w,  const float* __restrict__ reg_b,
                                 float* __restrict__ out) {
    const long long total = (long long)M_TOTAL * N_TOTAL;
    for (long long idx = blockIdx.x * 256LL + threadIdx.x; idx < total;
         idx += (long long)gridDim.x * 256LL) {
        const int m = (int)(idx / N_TOTAL);
        const int n = (int)(idx % N_TOTAL);
        const float* w; float b; size_t o;
        if      (n <   8) { w = conf_w + (size_t)n * HIDDEN;         b = conf_b[n];       o = (size_t)m * 8 + n; }
        else if (n < 136) { w = cls_w + (size_t)(n - 8) * HIDDEN;    b = cls_b[n - 8];    o = OFF_CLS + (size_t)m * 128 + (n - 8); }
        else              { w = reg_w + (size_t)(n - 136) * HIDDEN;  b = reg_b[n - 136];  o = OFF_REG + (size_t)m * 16 + (n - 136); }
        const float* x = hs + (size_t)m * HIDDEN;
        float s = 0.f;
        for (int k = 0; k < HIDDEN; k += 4) {
            f32x4 xv = *(const f32x4*)(x + k);
            f32x4 wv = *(const f32x4*)(w + k);
            s += xv[0] * wv[0] + xv[1] * wv[1] + xv[2] * wv[2] + xv[3] * wv[3];
        }
        out[o] = s + b;
    }
}

extern "C" void kernel_launch(void* const* d_in, const int* in_sizes, int n_in,
                              void* d_out, int out_size, void* d_ws, size_t ws_size,
                              hipStream_t stream) {
    const float* hs     = (const float*)d_in[0];
    const float* conf_w = (const float*)d_in[1];
    const float* conf_b = (const float*)d_in[2];
    const float* cls_w  = (const float*)d_in[3];
    const float* cls_b  = (const float*)d_in[4];
    const float* reg_w  = (const float*)d_in[5];
    const float* reg_b  = (const float*)d_in[6];
    float* out = (float*)d_out;

    const size_t ws_needed = 160 * (size_t)HIDDEN * sizeof(unsigned short); // 320 KB
    if (d_ws && ws_size >= ws_needed) {
        unsigned short* wbf = (unsigned short*)d_ws;
        convert_w_kernel<<<160, 256, 0, stream>>>(conf_w, cls_w, reg_w, wbf);
        ssd_mfma_kernel<<<512, 256, 0, stream>>>(hs, wbf, conf_b, cls_b, reg_b, out);
    } else {
        ssd_naive_kernel<<<2048, 256, 0, stream>>>(hs, conf_w, conf_b,
                                                   cls_w, cls_b, reg_w, reg_b, out);
    }
}